// Round 1
// baseline (442.493 us; speedup 1.0000x reference)
//
#include <hip/hip_runtime.h>
#include <hip/hip_bf16.h>
#include <stdint.h>

#define DEV __device__ __forceinline__

typedef float f32x4 __attribute__((ext_vector_type(4)));
typedef short s16x8 __attribute__((ext_vector_type(8)));
typedef __bf16 bf16x8 __attribute__((ext_vector_type(8)));
typedef unsigned short u16;

// ---------- helpers ----------
DEV u16 f2bf(float f) {  // round-to-nearest-even f32 -> bf16
  uint32_t u = __builtin_bit_cast(uint32_t, f);
  u += 0x7FFFu + ((u >> 16) & 1u);
  return (u16)(u >> 16);
}

DEV void gload16(const void* g, void* l) {
  __builtin_amdgcn_global_load_lds((__attribute__((address_space(1))) void*)(g),
                                   (__attribute__((address_space(3))) void*)(l),
                                   16, 0, 0);
}

DEV f32x4 mfma16(s16x8 a, s16x8 b, f32x4 c) {
  return __builtin_amdgcn_mfma_f32_16x16x32_bf16(
      __builtin_bit_cast(bf16x8, a), __builtin_bit_cast(bf16x8, b), c, 0, 0, 0);
}

// ---------- workspace layout (bytes) ----------
#define OFF_S0    0ul
#define OFF_S1    16384ul
#define OFF_SRGB  32768ul
#define OFF_D0    49152ul
#define OFF_D1    65536ul
#define OFF_WSQ0  81920ul
#define OFF_WSQ1  1130496ul
#define OFF_ZERO  2179072ul
#define OFF_X0M   2179328ul       // bf16 NHWC [8][32][32][512]
#define OFF_G     10567936ul      // bf16 [4 phase][9 tap][512 o][512 c]
#define OFF_W1T   29442304ul      // bf16 [9 tap][512 o][512 c]
#define OFF_X1M   34160896ul      // bf16 NHWC [8][64][64][512] (s1-modulated)
// total ~64.6 MB

// ---------- styles: s = ws @ affW^T / sqrt(512) + affB ----------
__global__ void styles_kernel(const float* __restrict__ wsv,
                              const float* __restrict__ a0w, const float* __restrict__ a0b,
                              const float* __restrict__ a1w, const float* __restrict__ a1b,
                              const float* __restrict__ argw, const float* __restrict__ argb,
                              float* __restrict__ s0, float* __restrict__ s1,
                              float* __restrict__ srgb) {
  const int idx = blockIdx.x * 4 + (threadIdx.x >> 6);  // 12288 wave-outputs
  const int lane = threadIdx.x & 63;
  const int l = idx >> 12, rem = idx & 4095, b = rem >> 9, o = rem & 511;
  const float* aw = (l == 0) ? a0w : ((l == 1) ? a1w : argw);
  const float* wrow = wsv + (b * 3 + l) * 512;
  const float* arow = aw + o * 512;
  float acc = 0.f;
#pragma unroll
  for (int k = 0; k < 8; ++k) acc += wrow[lane + 64 * k] * arow[lane + 64 * k];
#pragma unroll
  for (int off = 32; off; off >>= 1) acc += __shfl_xor(acc, off);
  if (lane == 0) {
    const float sg = 0.04419417382415922f;  // 1/sqrt(512)
    if (l == 0)      s0[b * 512 + o] = acc * sg + a0b[o];
    else if (l == 1) s1[b * 512 + o] = acc * sg + a1b[o];
    else             srgb[b * 512 + o] = (acc * sg + argb[o]) * sg;
  }
}

// ---------- conv0 combined weights G + wsq0 ----------
// G[sy][sx] = sum_{uy,ux} kk[sy-uy]*kk[sx-ux]*w0[2-uy][2-ux], kk = 2*[1,3,3,1]/8
// phase (py,px): tap (dyi,dxi) -> G[2*dyi+1-py][2*dxi+1-px]
__global__ void prepG_kernel(const float* __restrict__ w0, u16* __restrict__ G,
                             float* __restrict__ wsq0) {
  const int idx = blockIdx.x * 256 + threadIdx.x;  // o*512+c
  float w[9], sq = 0.f;
#pragma unroll
  for (int t = 0; t < 9; ++t) { w[t] = w0[idx * 9 + t]; sq += w[t] * w[t]; }
  wsq0[idx] = sq;
  const float kk[4] = {0.25f, 0.75f, 0.75f, 0.25f};
  float G2[6][6];
#pragma unroll
  for (int sy = 0; sy < 6; ++sy)
#pragma unroll
    for (int sx = 0; sx < 6; ++sx) {
      float a = 0.f;
#pragma unroll
      for (int uy = 0; uy < 3; ++uy) {
        const int ay = sy - uy;
        if (ay < 0 || ay > 3) continue;
#pragma unroll
        for (int ux = 0; ux < 3; ++ux) {
          const int ax = sx - ux;
          if (ax < 0 || ax > 3) continue;
          a += kk[ay] * kk[ax] * w[(2 - uy) * 3 + (2 - ux)];
        }
      }
      G2[sy][sx] = a;
    }
#pragma unroll
  for (int py = 0; py < 2; ++py)
#pragma unroll
    for (int px = 0; px < 2; ++px)
#pragma unroll
      for (int dyi = 0; dyi < 3; ++dyi)
#pragma unroll
        for (int dxi = 0; dxi < 3; ++dxi)
          G[(size_t)(((py * 2 + px) * 9) + dyi * 3 + dxi) * 262144 + idx] =
              f2bf(G2[2 * dyi + 1 - py][2 * dxi + 1 - px]);
}

// ---------- w1 -> [tap][o][c] bf16 + wsq1 ----------
__global__ void prepW1_kernel(const float* __restrict__ w1, u16* __restrict__ w1t,
                              float* __restrict__ wsq1) {
  const int idx = blockIdx.x * 256 + threadIdx.x;
  float w[9], sq = 0.f;
#pragma unroll
  for (int t = 0; t < 9; ++t) { w[t] = w1[idx * 9 + t]; sq += w[t] * w[t]; }
  wsq1[idx] = sq;
#pragma unroll
  for (int t = 0; t < 9; ++t) w1t[(size_t)t * 262144 + idx] = f2bf(w[t]);
}

// ---------- dcoef = rsqrt(sum_c s^2 * wsq + 1e-8) ----------
__global__ void dcoef_kernel(const float* __restrict__ s0, const float* __restrict__ s1,
                             const float* __restrict__ wsq0, const float* __restrict__ wsq1,
                             float* __restrict__ d0, float* __restrict__ d1) {
  const int idx = blockIdx.x * 4 + (threadIdx.x >> 6);  // 8192
  const int lane = threadIdx.x & 63;
  const int layer = idx >> 12, rem = idx & 4095, b = rem >> 9, o = rem & 511;
  const float* s = layer ? s1 : s0;
  const float* wsq = layer ? wsq1 : wsq0;
  float acc = 0.f;
#pragma unroll
  for (int k = 0; k < 8; ++k) {
    const int c = lane + 64 * k;
    const float sv = s[b * 512 + c];
    acc += sv * sv * wsq[o * 512 + c];
  }
#pragma unroll
  for (int off = 32; off; off >>= 1) acc += __shfl_xor(acc, off);
  if (lane == 0) (layer ? d1 : d0)[b * 512 + o] = 1.f / sqrtf(acc + 1e-8f);
}

// ---------- x -> NHWC bf16 modulated by s0 ----------
__global__ void x0m_kernel(const float* __restrict__ x, const float* __restrict__ s0,
                           u16* __restrict__ out) {
  __shared__ u16 t[32 * 514];
  const int b = blockIdx.x >> 5, h = blockIdx.x & 31;
  const int tid = threadIdx.x;
  const int w = tid & 31, cs = tid >> 5;
  for (int c0 = 0; c0 < 512; c0 += 8) {
    const int c = c0 + cs;
    t[w * 514 + c] = f2bf(x[((b * 512 + c) * 32 + h) * 32 + w] * s0[b * 512 + c]);
  }
  __syncthreads();
  const int base = ((b * 32 + h) * 32) * 512;
  for (int i = 0; i < 64; ++i) {
    const int idx = i * 256 + tid;
    out[base + idx] = t[(idx >> 9) * 514 + (idx & 511)];
  }
}

// ---------- shared implicit-GEMM MFMA conv (3x3, pad 1) ----------
// CONV0: input x0m (32x32 NHWC), weights G[phase], epilogue -> x1m bf16 (s1-modulated),
//        output pixel (2*ty+py, 2*tx+px)
// CONV1: input x1m (64x64 NHWC), weights w1t, epilogue -> d_out f32 NCHW
template <int H, bool CONV0>
__global__ __launch_bounds__(256, 2) void conv_mfma_kernel(
    const u16* __restrict__ xin, const u16* __restrict__ wt,
    const float* __restrict__ dcoef, const float* __restrict__ bias,
    const float* __restrict__ noise, const float* __restrict__ nstr,
    const float* __restrict__ s_next, float* __restrict__ out_f32,
    u16* __restrict__ out_bf16, const char* __restrict__ zerobuf) {
  constexpr int W = H;
  constexpr int WC = W + 2;
  constexpr int ROWS = CONV0 ? 10 : 6;       // staged input rows
  constexpr int BU_REAL = 4 * ROWS * WC;     // 1360 / 1584 16B-units
  constexpr int NB_IT = (BU_REAL + 255) / 256;
  constexpr int BU_PAD = NB_IT * 256;        // 1536 / 1792
  constexpr int A_OFF = BU_PAD * 16;
  __shared__ __align__(16) char smem[(BU_PAD + 2304) * 16];  // 60/64 KiB

  const int tid = threadIdx.x;
  const int lane = tid & 63;
  const int wid = tid >> 6;
  const int l15 = lane & 15;
  const int l4 = lane >> 4;

  int bid = blockIdx.x;
  const int obIdx = bid & 7; bid >>= 3;
  int tile, phase, b;
  if (CONV0) { tile = bid & 3; phase = (bid >> 2) & 3; b = bid >> 4; }
  else       { tile = bid & 15; phase = 0; b = bid >> 4; }
  const int obase = obIdx * 64;
  const int row0 = CONV0 ? (tile * 8 - 1) : (tile * 4 - 1);

  // B staging descriptors (LDS unit u = (row*4 + k8)*WC + col)
  int boff[NB_IT];
  bool bval[NB_IT];
#pragma unroll
  for (int i = 0; i < NB_IT; ++i) {
    const int u = i * 256 + tid;
    const int row = u / (4 * WC);
    const int rem = u - row * (4 * WC);
    const int k8 = rem / WC;
    const int col = rem - k8 * WC;
    const int ir = row0 + row;
    const int ic = col - 1;
    bval[i] = (row < ROWS) && (ir >= 0) && (ir < H) && (ic >= 0) && (ic < W);
    boff[i] = (((b * H + ir) * W + ic) * 512 + k8 * 8) * 2;
  }

  // per-wave pixel tile: p = wid*64 + bc*16 + l15
  int prow[4], pcol[4], ub[4];
#pragma unroll
  for (int bc = 0; bc < 4; ++bc) {
    const int p = wid * 64 + bc * 16 + l15;
    prow[bc] = CONV0 ? (p >> 5) : (p >> 6);
    pcol[bc] = CONV0 ? (p & 31) : (p & 63);
    ub[bc] = ((prow[bc] * 4 + l4) * WC + pcol[bc]) * 16;
  }

  const u16* wtp = wt + (CONV0 ? (size_t)phase * 9 * 262144 : 0);

  f32x4 acc[4][4];
  const f32x4 fz = {0.f, 0.f, 0.f, 0.f};
#pragma unroll
  for (int i = 0; i < 4; ++i)
#pragma unroll
    for (int j = 0; j < 4; ++j) acc[i][j] = fz;

  for (int c0 = 0; c0 < 512; c0 += 32) {
#pragma unroll
    for (int i = 0; i < NB_IT; ++i) {
      const void* src = bval[i] ? (const void*)((const char*)xin + (boff[i] + c0 * 2))
                                : (const void*)zerobuf;
      gload16(src, smem + (i * 256 + wid * 64) * 16);
    }
#pragma unroll
    for (int t = 0; t < 9; ++t) {
      const void* src = (const void*)(wtp + ((size_t)(t * 512 + obase + lane) * 512 + c0 + wid * 8));
      gload16(src, smem + A_OFF + (t * 256 + wid * 64) * 16);
    }
    __syncthreads();
#pragma unroll
    for (int t = 0; t < 9; ++t) {
      const int dyi = t / 3, dxi = t % 3;
      s16x8 bfr[4], afr[4];
#pragma unroll
      for (int bc = 0; bc < 4; ++bc)
        bfr[bc] = *(const s16x8*)(smem + (ub[bc] + (dyi * 4 * WC + dxi) * 16));
#pragma unroll
      for (int f = 0; f < 4; ++f)
        afr[f] = *(const s16x8*)(smem + A_OFF + t * 4096 + (l4 * 64 + f * 16 + l15) * 16);
#pragma unroll
      for (int f = 0; f < 4; ++f)
#pragma unroll
        for (int bc = 0; bc < 4; ++bc)
          acc[f][bc] = mfma16(afr[f], bfr[bc], acc[f][bc]);
    }
    __syncthreads();
  }

  // epilogue: demod + noise + bias + lrelu*sqrt(2) + clamp (+ s1 modulation for CONV0)
  const float ns = nstr[0];
#pragma unroll
  for (int f = 0; f < 4; ++f) {
    const int o = obase + f * 16 + l4 * 4;
    const f32x4 dc = *(const f32x4*)(dcoef + b * 512 + o);
    const f32x4 bs = *(const f32x4*)(bias + o);
    f32x4 sn = fz;
    if constexpr (CONV0) sn = *(const f32x4*)(s_next + b * 512 + o);
#pragma unroll
    for (int bc = 0; bc < 4; ++bc) {
      int jy, jx;
      if constexpr (CONV0) {
        jy = 2 * (tile * 8 + prow[bc]) + (phase >> 1);
        jx = 2 * pcol[bc] + (phase & 1);
      } else {
        jy = tile * 4 + prow[bc];
        jx = pcol[bc];
      }
      const float nz = noise[jy * 64 + jx] * ns;
      float v[4];
#pragma unroll
      for (int r = 0; r < 4; ++r) {
        float xv = acc[f][bc][r] * dc[r] + nz + bs[r];
        xv = (xv < 0.f ? 0.2f * xv : xv) * 1.4142135623730951f;
        v[r] = fminf(fmaxf(xv, -256.f), 256.f);
      }
      if constexpr (CONV0) {
        ushort4 pk;
        pk.x = f2bf(v[0] * sn[0]);
        pk.y = f2bf(v[1] * sn[1]);
        pk.z = f2bf(v[2] * sn[2]);
        pk.w = f2bf(v[3] * sn[3]);
        *(ushort4*)(out_bf16 + ((size_t)((b * 64 + jy) * 64 + jx) * 512 + o)) = pk;
      } else {
#pragma unroll
        for (int r = 0; r < 4; ++r)
          out_f32[((size_t)(b * 512 + o + r) * 64 + jy) * 64 + jx] = v[r];
      }
    }
  }
}

// ---------- torgb (1x1 mod conv, f32) + img upsample + add ----------
__global__ void torgb_kernel(const float* __restrict__ xw, const float* __restrict__ img,
                             const float* __restrict__ srgb, const float* __restrict__ wrgb,
                             const float* __restrict__ brgb, float* __restrict__ imgout) {
  __shared__ float red[4][3][64];
  const int b = blockIdx.x >> 6, jy = blockIdx.x & 63;
  const int tid = threadIdx.x;
  const int jx = tid & 63, cg = tid >> 6;
  float p0 = 0.f, p1 = 0.f, p2 = 0.f;
  const float* xb = xw + ((size_t)(b * 512 + cg * 128) * 64 + jy) * 64 + jx;
  const float* sb = srgb + b * 512 + cg * 128;
  for (int i = 0; i < 128; ++i) {
    const float xs = xb[(size_t)i * 4096] * sb[i];
    const int c = cg * 128 + i;
    p0 += xs * wrgb[c];
    p1 += xs * wrgb[512 + c];
    p2 += xs * wrgb[1024 + c];
  }
  red[cg][0][jx] = p0; red[cg][1][jx] = p1; red[cg][2][jx] = p2;
  __syncthreads();
  if (cg == 0) {
    const int qy = jy >> 1, qx = jx >> 1;
    int ry[2]; float wy[2];
    if ((jy & 1) == 0) { ry[0] = qy - 1; wy[0] = 0.25f; ry[1] = qy; wy[1] = 0.75f; }
    else               { ry[0] = qy;     wy[0] = 0.75f; ry[1] = qy + 1; wy[1] = 0.25f; }
    int rx[2]; float wx[2];
    if ((jx & 1) == 0) { rx[0] = qx - 1; wx[0] = 0.25f; rx[1] = qx; wx[1] = 0.75f; }
    else               { rx[0] = qx;     wx[0] = 0.75f; rx[1] = qx + 1; wx[1] = 0.25f; }
#pragma unroll
    for (int o = 0; o < 3; ++o) {
      float y = red[0][o][jx] + red[1][o][jx] + red[2][o][jx] + red[3][o][jx] + brgb[o];
      y = fminf(fmaxf(y, -256.f), 256.f);
      float iv = 0.f;
#pragma unroll
      for (int a = 0; a < 2; ++a)
#pragma unroll
        for (int e = 0; e < 2; ++e)
          if (ry[a] >= 0 && ry[a] < 32 && rx[e] >= 0 && rx[e] < 32)
            iv += wy[a] * wx[e] * img[((b * 3 + o) * 32 + ry[a]) * 32 + rx[e]];
      imgout[((b * 3 + o) * 64 + jy) * 64 + jx] = y + iv;
    }
  }
}

// ---------- launch ----------
extern "C" void kernel_launch(void* const* d_in, const int* in_sizes, int n_in,
                              void* d_out, int out_size, void* d_ws, size_t ws_size,
                              hipStream_t stream) {
  (void)in_sizes; (void)n_in; (void)out_size; (void)ws_size;
  const float* x    = (const float*)d_in[0];
  const float* img  = (const float*)d_in[1];
  const float* wsv  = (const float*)d_in[2];
  const float* a0w  = (const float*)d_in[3];
  const float* a0b  = (const float*)d_in[4];
  const float* w0   = (const float*)d_in[5];
  const float* b0   = (const float*)d_in[6];
  const float* ns0  = (const float*)d_in[7];
  const float* nc0  = (const float*)d_in[8];
  const float* a1w  = (const float*)d_in[9];
  const float* a1b  = (const float*)d_in[10];
  const float* w1   = (const float*)d_in[11];
  const float* b1   = (const float*)d_in[12];
  const float* ns1  = (const float*)d_in[13];
  const float* nc1  = (const float*)d_in[14];
  const float* argw = (const float*)d_in[15];
  const float* argb = (const float*)d_in[16];
  const float* wrgb = (const float*)d_in[17];
  const float* brgb = (const float*)d_in[18];

  char* wsb = (char*)d_ws;
  float* s0   = (float*)(wsb + OFF_S0);
  float* s1   = (float*)(wsb + OFF_S1);
  float* srgb = (float*)(wsb + OFF_SRGB);
  float* dd0  = (float*)(wsb + OFF_D0);
  float* dd1  = (float*)(wsb + OFF_D1);
  float* wsq0 = (float*)(wsb + OFF_WSQ0);
  float* wsq1 = (float*)(wsb + OFF_WSQ1);
  char*  zero = wsb + OFF_ZERO;
  u16*   x0m  = (u16*)(wsb + OFF_X0M);
  u16*   G    = (u16*)(wsb + OFF_G);
  u16*   w1t  = (u16*)(wsb + OFF_W1T);
  u16*   x1m  = (u16*)(wsb + OFF_X1M);

  float* out_x   = (float*)d_out;
  float* out_img = out_x + 16777216;

  hipMemsetAsync(zero, 0, 256, stream);
  styles_kernel<<<3072, 256, 0, stream>>>(wsv, a0w, a0b, a1w, a1b, argw, argb, s0, s1, srgb);
  prepG_kernel<<<1024, 256, 0, stream>>>(w0, G, wsq0);
  prepW1_kernel<<<1024, 256, 0, stream>>>(w1, w1t, wsq1);
  dcoef_kernel<<<2048, 256, 0, stream>>>(s0, s1, wsq0, wsq1, dd0, dd1);
  x0m_kernel<<<256, 256, 0, stream>>>(x, s0, x0m);
  conv_mfma_kernel<32, true><<<1024, 256, 0, stream>>>(
      x0m, G, dd0, b0, nc0, ns0, s1, nullptr, x1m, zero);
  conv_mfma_kernel<64, false><<<1024, 256, 0, stream>>>(
      x1m, w1t, dd1, b1, nc1, ns1, nullptr, out_x, nullptr, zero);
  torgb_kernel<<<512, 256, 0, stream>>>(out_x, img, srgb, wrgb, brgb, out_img);
}

// Round 3
// 431.136 us; speedup vs baseline: 1.0263x; 1.0263x over previous
//
#include <hip/hip_runtime.h>
#include <hip/hip_bf16.h>
#include <stdint.h>

#define DEV __device__ __forceinline__

typedef float f32x4 __attribute__((ext_vector_type(4)));
typedef short s16x8 __attribute__((ext_vector_type(8)));
typedef __bf16 bf16x8 __attribute__((ext_vector_type(8)));
typedef unsigned short u16;

// ---------- helpers ----------
DEV u16 f2bf(float f) {  // round-to-nearest-even f32 -> bf16
  uint32_t u = __builtin_bit_cast(uint32_t, f);
  u += 0x7FFFu + ((u >> 16) & 1u);
  return (u16)(u >> 16);
}

DEV void gload16(const void* g, void* l) {
  __builtin_amdgcn_global_load_lds((__attribute__((address_space(1))) void*)(g),
                                   (__attribute__((address_space(3))) void*)(l),
                                   16, 0, 0);
}

DEV f32x4 mfma16(s16x8 a, s16x8 b, f32x4 c) {
  return __builtin_amdgcn_mfma_f32_16x16x32_bf16(
      __builtin_bit_cast(bf16x8, a), __builtin_bit_cast(bf16x8, b), c, 0, 0, 0);
}

// ---------- workspace layout (bytes) ----------
#define OFF_S0    0ul
#define OFF_S1    16384ul
#define OFF_SRGB  32768ul
#define OFF_D0    49152ul
#define OFF_D1    65536ul
#define OFF_WSQ0  81920ul
#define OFF_WSQ1  1130496ul
#define OFF_ZERO  2179072ul
#define OFF_X0M   2179328ul       // bf16 NHWC [8][32][32][512]
#define OFF_G     10567936ul      // bf16 [4 phase][9 tap][512 o][512 c]
#define OFF_W1T   29442304ul      // bf16 [9 tap][512 o][512 c]
#define OFF_X1M   34160896ul      // bf16 NHWC [8][64][64][512] (s1-modulated)

// ---------- styles ----------
__global__ void styles_kernel(const float* __restrict__ wsv,
                              const float* __restrict__ a0w, const float* __restrict__ a0b,
                              const float* __restrict__ a1w, const float* __restrict__ a1b,
                              const float* __restrict__ argw, const float* __restrict__ argb,
                              float* __restrict__ s0, float* __restrict__ s1,
                              float* __restrict__ srgb) {
  const int idx = blockIdx.x * 4 + (threadIdx.x >> 6);
  const int lane = threadIdx.x & 63;
  const int l = idx >> 12, rem = idx & 4095, b = rem >> 9, o = rem & 511;
  const float* aw = (l == 0) ? a0w : ((l == 1) ? a1w : argw);
  const float* wrow = wsv + (b * 3 + l) * 512;
  const float* arow = aw + o * 512;
  float acc = 0.f;
#pragma unroll
  for (int k = 0; k < 8; ++k) acc += wrow[lane + 64 * k] * arow[lane + 64 * k];
#pragma unroll
  for (int off = 32; off; off >>= 1) acc += __shfl_xor(acc, off);
  if (lane == 0) {
    const float sg = 0.04419417382415922f;  // 1/sqrt(512)
    if (l == 0)      s0[b * 512 + o] = acc * sg + a0b[o];
    else if (l == 1) s1[b * 512 + o] = acc * sg + a1b[o];
    else             srgb[b * 512 + o] = (acc * sg + argb[o]) * sg;
  }
}

// ---------- conv0 combined weights G + wsq0 ----------
__global__ void prepG_kernel(const float* __restrict__ w0, u16* __restrict__ G,
                             float* __restrict__ wsq0) {
  const int idx = blockIdx.x * 256 + threadIdx.x;  // o*512+c
  float w[9], sq = 0.f;
#pragma unroll
  for (int t = 0; t < 9; ++t) { w[t] = w0[idx * 9 + t]; sq += w[t] * w[t]; }
  wsq0[idx] = sq;
  const float kk[4] = {0.25f, 0.75f, 0.75f, 0.25f};
  float G2[6][6];
#pragma unroll
  for (int sy = 0; sy < 6; ++sy)
#pragma unroll
    for (int sx = 0; sx < 6; ++sx) {
      float a = 0.f;
#pragma unroll
      for (int uy = 0; uy < 3; ++uy) {
        const int ay = sy - uy;
        if (ay < 0 || ay > 3) continue;
#pragma unroll
        for (int ux = 0; ux < 3; ++ux) {
          const int ax = sx - ux;
          if (ax < 0 || ax > 3) continue;
          a += kk[ay] * kk[ax] * w[(2 - uy) * 3 + (2 - ux)];
        }
      }
      G2[sy][sx] = a;
    }
#pragma unroll
  for (int py = 0; py < 2; ++py)
#pragma unroll
    for (int px = 0; px < 2; ++px)
#pragma unroll
      for (int dyi = 0; dyi < 3; ++dyi)
#pragma unroll
        for (int dxi = 0; dxi < 3; ++dxi)
          G[(size_t)(((py * 2 + px) * 9) + dyi * 3 + dxi) * 262144 + idx] =
              f2bf(G2[2 * dyi + 1 - py][2 * dxi + 1 - px]);
}

// ---------- w1 -> [tap][o][c] bf16 + wsq1 ----------
__global__ void prepW1_kernel(const float* __restrict__ w1, u16* __restrict__ w1t,
                              float* __restrict__ wsq1) {
  const int idx = blockIdx.x * 256 + threadIdx.x;
  float w[9], sq = 0.f;
#pragma unroll
  for (int t = 0; t < 9; ++t) { w[t] = w1[idx * 9 + t]; sq += w[t] * w[t]; }
  wsq1[idx] = sq;
#pragma unroll
  for (int t = 0; t < 9; ++t) w1t[(size_t)t * 262144 + idx] = f2bf(w[t]);
}

// ---------- dcoef ----------
__global__ void dcoef_kernel(const float* __restrict__ s0, const float* __restrict__ s1,
                             const float* __restrict__ wsq0, const float* __restrict__ wsq1,
                             float* __restrict__ d0, float* __restrict__ d1) {
  const int idx = blockIdx.x * 4 + (threadIdx.x >> 6);
  const int lane = threadIdx.x & 63;
  const int layer = idx >> 12, rem = idx & 4095, b = rem >> 9, o = rem & 511;
  const float* s = layer ? s1 : s0;
  const float* wsq = layer ? wsq1 : wsq0;
  float acc = 0.f;
#pragma unroll
  for (int k = 0; k < 8; ++k) {
    const int c = lane + 64 * k;
    const float sv = s[b * 512 + c];
    acc += sv * sv * wsq[o * 512 + c];
  }
#pragma unroll
  for (int off = 32; off; off >>= 1) acc += __shfl_xor(acc, off);
  if (lane == 0) (layer ? d1 : d0)[b * 512 + o] = 1.f / sqrtf(acc + 1e-8f);
}

// ---------- x -> NHWC bf16 modulated by s0 ----------
__global__ void x0m_kernel(const float* __restrict__ x, const float* __restrict__ s0,
                           u16* __restrict__ out) {
  __shared__ u16 t[32 * 514];
  const int b = blockIdx.x >> 5, h = blockIdx.x & 31;
  const int tid = threadIdx.x;
  const int w = tid & 31, cs = tid >> 5;
  for (int c0 = 0; c0 < 512; c0 += 8) {
    const int c = c0 + cs;
    t[w * 514 + c] = f2bf(x[((b * 512 + c) * 32 + h) * 32 + w] * s0[b * 512 + c]);
  }
  __syncthreads();
  const int base = ((b * 32 + h) * 32) * 512;
  for (int i = 0; i < 64; ++i) {
    const int idx = i * 256 + tid;
    out[base + idx] = t[(idx >> 9) * 514 + (idx & 511)];
  }
}

// ---------- pipelined implicit-GEMM MFMA conv (3x3, pad 1) ----------
// 144 tap-phases (16 c-chunks x 9 taps), counted-vmcnt pipeline (T3+T4+T5):
// per phase: issue next-tap A-chunk (dbuf) + one of 6 next-c0 B-chunks (dbuf),
// s_waitcnt vmcnt(N) with exact counts (never 0 mid-loop), raw s_barrier,
// ds_read 4 A-frags + 4 B-frags, setprio(1) around 16 MFMA, barrier.
// All global_load_lds LDS bases are WAVE-UNIFORM (wid only); HW adds lane*16.
// A LDS layout per chunk: unit = k8*64 + cout_l (lanes read consecutive 16B).
// LDS: A 2x4096 @0, B 2x24576 @8192 -> 57344 B, 2 blocks/CU.
template <int H, bool CONV0>
__global__ __launch_bounds__(256, 2) void conv_mfma_kernel(
    const u16* __restrict__ xin, const u16* __restrict__ wt,
    const float* __restrict__ dcoef, const float* __restrict__ bias,
    const float* __restrict__ noise, const float* __restrict__ nstr,
    const float* __restrict__ s_next, float* __restrict__ out_f32,
    u16* __restrict__ out_bf16, const char* __restrict__ zerobuf) {
  constexpr int W = H;
  __shared__ __align__(16) char smem[57344];

  const int tid = threadIdx.x;
  const int lane = tid & 63;
  const int wid = tid >> 6;
  const int l15 = lane & 15;
  const int l4 = lane >> 4;

  int bid = blockIdx.x;
  const int obIdx = bid & 7; bid >>= 3;
  int tile, phase, b, rt, ct;
  if (CONV0) { tile = bid & 3; phase = (bid >> 2) & 3; b = bid >> 4; rt = tile; ct = 0; }
  else       { tile = bid & 15; phase = 0; b = bid >> 4; rt = tile >> 1; ct = tile & 1; }
  const int obase = obIdx * 64;
  const int row0 = rt * 8 - 1;
  const int col0 = ct * 32 - 1;

  // B chunk descriptors: LDS unit u = (row*4+k8)*34 + col, 1360 real units, 6x256 chunks
  size_t boff[6];
  bool bvalid[6];
#pragma unroll
  for (int i = 0; i < 6; ++i) {
    const int u = i * 256 + tid;
    const int row = u / 136;
    const int rem = u - row * 136;
    const int k8 = rem / 34;
    const int col = rem - k8 * 34;
    const int ir = row0 + row;
    const int ic = col0 + col;
    bvalid[i] = (u < 1360) && (ir >= 0) && (ir < H) && (ic >= 0) && (ic < W);
    boff[i] = ((size_t)((b * H + ir) * W + ic) * 512 + k8 * 8) * 2;
  }

  // per-wave pixel frags: p = wid*64 + bc*16 + l15 over 8x32 tile
  int ub[4], jy[4], jx[4];
#pragma unroll
  for (int bc = 0; bc < 4; ++bc) {
    const int p = wid * 64 + bc * 16 + l15;
    const int pr = p >> 5, pc = p & 31;
    ub[bc] = ((pr * 4 + l4) * 34 + pc) * 16;
    if (CONV0) { jy[bc] = 2 * (rt * 8 + pr) + (phase >> 1); jx[bc] = 2 * pc + (phase & 1); }
    else       { jy[bc] = rt * 8 + pr; jx[bc] = ct * 32 + pc; }
  }

  const u16* wtp = wt + (CONV0 ? (size_t)phase * 9 * 262144 : 0);
  const char* wtA = (const char*)wtp;
  const char* xin_c = (const char*)xin;
  // A staging (round-1 verified layout): unit = k8*64 + cout_l; thread tid writes
  // unit wid*64+lane -> k8=wid, cout_l=lane; global src (t*512+obase+lane)*512+c0+wid*8
  const size_t aoff = ((size_t)(obase + lane) * 512 + (size_t)wid * 8) * 2;
  const int ldsAw = wid * 1024;                 // wave-uniform A dest (per 4096B chunk)
  const int ldsBw = wid * 1024;                 // wave-uniform B dest (per 256-unit chunk)

  f32x4 acc[4][4];
  const f32x4 fz = {0.f, 0.f, 0.f, 0.f};
#pragma unroll
  for (int i = 0; i < 4; ++i)
#pragma unroll
    for (int j = 0; j < 4; ++j) acc[i][j] = fz;

  // ---- prologue: A(tap0,c0) + all 6 B chunks of c0 ----
  gload16(wtA + aoff, smem + ldsAw);
#pragma unroll
  for (int ch = 0; ch < 6; ++ch) {
    const void* src = bvalid[ch] ? (const void*)(xin_c + boff[ch]) : (const void*)zerobuf;
    gload16(src, smem + 8192 + ch * 4096 + ldsBw);
  }
  asm volatile("s_waitcnt vmcnt(0)" ::: "memory");
  __builtin_amdgcn_s_barrier();

#define CONV_PH(tt, NW, DO_A, DO_B, AIC)                                        \
  {                                                                             \
    if (DO_A) {                                                                 \
      const int nt_ = ((tt) == 8) ? 0 : ((tt) + 1);                             \
      const int nc_ = ((tt) == 8) ? ((AIC) + 1) : (AIC);                        \
      const int nap_ = ((AIC) + (tt) + 1) & 1;                                  \
      gload16(wtA + aoff + (size_t)nt_ * 524288 + (size_t)nc_ * 64,             \
              smem + nap_ * 4096 + ldsAw);                                      \
    }                                                                           \
    if (DO_B && (tt) < 6) {                                                     \
      const void* src_ = bvalid[(tt)] ? (const void*)(xin_c + boff[(tt)] +      \
                            (size_t)((AIC) + 1) * 64) : (const void*)zerobuf;   \
      gload16(src_, smem + 8192 + (((AIC) + 1) & 1) * 24576 +                   \
              (tt) * 4096 + ldsBw);                                             \
    }                                                                           \
    asm volatile("s_waitcnt vmcnt(" NW ")" ::: "memory");                       \
    __builtin_amdgcn_s_barrier();                                               \
    const char* Ab_ = smem + (((AIC) + (tt)) & 1) * 4096;                       \
    const char* Bb_ = smem + 8192 + ((AIC) & 1) * 24576;                        \
    s16x8 afr_[4], bfr_[4];                                                     \
    _Pragma("unroll")                                                           \
    for (int f_ = 0; f_ < 4; ++f_)                                              \
      afr_[f_] = *(const s16x8*)(Ab_ + (l4 * 64 + f_ * 16 + l15) * 16);         \
    _Pragma("unroll")                                                           \
    for (int bc_ = 0; bc_ < 4; ++bc_)                                           \
      bfr_[bc_] = *(const s16x8*)(Bb_ + ub[bc_] +                               \
                                  (((tt) / 3) * 136 + ((tt) % 3)) * 16);        \
    __builtin_amdgcn_s_setprio(1);                                              \
    _Pragma("unroll")                                                           \
    for (int f_ = 0; f_ < 4; ++f_)                                              \
      _Pragma("unroll")                                                         \
      for (int bc_ = 0; bc_ < 4; ++bc_)                                         \
        acc[f_][bc_] = mfma16(afr_[f_], bfr_[bc_], acc[f_][bc_]);               \
    __builtin_amdgcn_s_setprio(0);                                              \
    __builtin_amdgcn_s_barrier();                                               \
  }

#pragma unroll 1
  for (int c0i = 0; c0i < 15; ++c0i) {
    CONV_PH(0, "2", true, true, c0i)
    CONV_PH(1, "3", true, true, c0i)
    CONV_PH(2, "3", true, true, c0i)
    CONV_PH(3, "3", true, true, c0i)
    CONV_PH(4, "3", true, true, c0i)
    CONV_PH(5, "3", true, true, c0i)
    CONV_PH(6, "2", true, true, c0i)
    CONV_PH(7, "1", true, true, c0i)
    CONV_PH(8, "1", true, true, c0i)
  }
  // tail c0i = 15: no B issues; A issues while they exist; exact waits
  CONV_PH(0, "1", true, false, 15)
  CONV_PH(1, "1", true, false, 15)
  CONV_PH(2, "1", true, false, 15)
  CONV_PH(3, "1", true, false, 15)
  CONV_PH(4, "1", true, false, 15)
  CONV_PH(5, "1", true, false, 15)
  CONV_PH(6, "1", true, false, 15)
  CONV_PH(7, "1", true, false, 15)
  CONV_PH(8, "0", false, false, 15)
#undef CONV_PH

  // epilogue: demod + noise + bias + lrelu*sqrt(2) + clamp (+ s1 mod for CONV0)
  const float ns = nstr[0];
#pragma unroll
  for (int f = 0; f < 4; ++f) {
    const int o = obase + f * 16 + l4 * 4;
    const f32x4 dc = *(const f32x4*)(dcoef + b * 512 + o);
    const f32x4 bs = *(const f32x4*)(bias + o);
    f32x4 sn = fz;
    if constexpr (CONV0) sn = *(const f32x4*)(s_next + b * 512 + o);
#pragma unroll
    for (int bc = 0; bc < 4; ++bc) {
      const float nz = noise[jy[bc] * 64 + jx[bc]] * ns;
      float v[4];
#pragma unroll
      for (int r = 0; r < 4; ++r) {
        float xv = acc[f][bc][r] * dc[r] + nz + bs[r];
        xv = (xv < 0.f ? 0.2f * xv : xv) * 1.4142135623730951f;
        v[r] = fminf(fmaxf(xv, -256.f), 256.f);
      }
      if constexpr (CONV0) {
        ushort4 pk;
        pk.x = f2bf(v[0] * sn[0]);
        pk.y = f2bf(v[1] * sn[1]);
        pk.z = f2bf(v[2] * sn[2]);
        pk.w = f2bf(v[3] * sn[3]);
        *(ushort4*)(out_bf16 + ((size_t)((b * 64 + jy[bc]) * 64 + jx[bc]) * 512 + o)) = pk;
      } else {
#pragma unroll
        for (int r = 0; r < 4; ++r)
          out_f32[((size_t)(b * 512 + o + r) * 64 + jy[bc]) * 64 + jx[bc]] = v[r];
      }
    }
  }
}

// ---------- torgb (1x1 mod conv, f32) + img upsample + add ----------
__global__ void torgb_kernel(const float* __restrict__ xw, const float* __restrict__ img,
                             const float* __restrict__ srgb, const float* __restrict__ wrgb,
                             const float* __restrict__ brgb, float* __restrict__ imgout) {
  __shared__ float red[4][3][64];
  const int b = blockIdx.x >> 6, jy = blockIdx.x & 63;
  const int tid = threadIdx.x;
  const int jx = tid & 63, cg = tid >> 6;
  float p0 = 0.f, p1 = 0.f, p2 = 0.f;
  const float* xb = xw + ((size_t)(b * 512 + cg * 128) * 64 + jy) * 64 + jx;
  const float* sb = srgb + b * 512 + cg * 128;
  for (int i = 0; i < 128; ++i) {
    const float xs = xb[(size_t)i * 4096] * sb[i];
    const int c = cg * 128 + i;
    p0 += xs * wrgb[c];
    p1 += xs * wrgb[512 + c];
    p2 += xs * wrgb[1024 + c];
  }
  red[cg][0][jx] = p0; red[cg][1][jx] = p1; red[cg][2][jx] = p2;
  __syncthreads();
  if (cg == 0) {
    const int qy = jy >> 1, qx = jx >> 1;
    int ry[2]; float wy[2];
    if ((jy & 1) == 0) { ry[0] = qy - 1; wy[0] = 0.25f; ry[1] = qy; wy[1] = 0.75f; }
    else               { ry[0] = qy;     wy[0] = 0.75f; ry[1] = qy + 1; wy[1] = 0.25f; }
    int rx[2]; float wx[2];
    if ((jx & 1) == 0) { rx[0] = qx - 1; wx[0] = 0.25f; rx[1] = qx; wx[1] = 0.75f; }
    else               { rx[0] = qx;     wx[0] = 0.75f; rx[1] = qx + 1; wx[1] = 0.25f; }
#pragma unroll
    for (int o = 0; o < 3; ++o) {
      float y = red[0][o][jx] + red[1][o][jx] + red[2][o][jx] + red[3][o][jx] + brgb[o];
      y = fminf(fmaxf(y, -256.f), 256.f);
      float iv = 0.f;
#pragma unroll
      for (int a = 0; a < 2; ++a)
#pragma unroll
        for (int e = 0; e < 2; ++e)
          if (ry[a] >= 0 && ry[a] < 32 && rx[e] >= 0 && rx[e] < 32)
            iv += wy[a] * wx[e] * img[((b * 3 + o) * 32 + ry[a]) * 32 + rx[e]];
      imgout[((b * 3 + o) * 64 + jy) * 64 + jx] = y + iv;
    }
  }
}

// ---------- launch ----------
extern "C" void kernel_launch(void* const* d_in, const int* in_sizes, int n_in,
                              void* d_out, int out_size, void* d_ws, size_t ws_size,
                              hipStream_t stream) {
  (void)in_sizes; (void)n_in; (void)out_size; (void)ws_size;
  const float* x    = (const float*)d_in[0];
  const float* img  = (const float*)d_in[1];
  const float* wsv  = (const float*)d_in[2];
  const float* a0w  = (const float*)d_in[3];
  const float* a0b  = (const float*)d_in[4];
  const float* w0   = (const float*)d_in[5];
  const float* b0   = (const float*)d_in[6];
  const float* ns0  = (const float*)d_in[7];
  const float* nc0  = (const float*)d_in[8];
  const float* a1w  = (const float*)d_in[9];
  const float* a1b  = (const float*)d_in[10];
  const float* w1   = (const float*)d_in[11];
  const float* b1   = (const float*)d_in[12];
  const float* ns1  = (const float*)d_in[13];
  const float* nc1  = (const float*)d_in[14];
  const float* argw = (const float*)d_in[15];
  const float* argb = (const float*)d_in[16];
  const float* wrgb = (const float*)d_in[17];
  const float* brgb = (const float*)d_in[18];

  char* wsb = (char*)d_ws;
  float* s0   = (float*)(wsb + OFF_S0);
  float* s1   = (float*)(wsb + OFF_S1);
  float* srgb = (float*)(wsb + OFF_SRGB);
  float* dd0  = (float*)(wsb + OFF_D0);
  float* dd1  = (float*)(wsb + OFF_D1);
  float* wsq0 = (float*)(wsb + OFF_WSQ0);
  float* wsq1 = (float*)(wsb + OFF_WSQ1);
  char*  zero = wsb + OFF_ZERO;
  u16*   x0m  = (u16*)(wsb + OFF_X0M);
  u16*   G    = (u16*)(wsb + OFF_G);
  u16*   w1t  = (u16*)(wsb + OFF_W1T);
  u16*   x1m  = (u16*)(wsb + OFF_X1M);

  float* out_x   = (float*)d_out;
  float* out_img = out_x + 16777216;

  hipMemsetAsync(zero, 0, 256, stream);
  styles_kernel<<<3072, 256, 0, stream>>>(wsv, a0w, a0b, a1w, a1b, argw, argb, s0, s1, srgb);
  prepG_kernel<<<1024, 256, 0, stream>>>(w0, G, wsq0);
  prepW1_kernel<<<1024, 256, 0, stream>>>(w1, w1t, wsq1);
  dcoef_kernel<<<2048, 256, 0, stream>>>(s0, s1, wsq0, wsq1, dd0, dd1);
  x0m_kernel<<<256, 256, 0, stream>>>(x, s0, x0m);
  conv_mfma_kernel<32, true><<<1024, 256, 0, stream>>>(
      x0m, G, dd0, b0, nc0, ns0, s1, nullptr, x1m, zero);
  conv_mfma_kernel<64, false><<<1024, 256, 0, stream>>>(
      x1m, w1t, dd1, b1, nc1, ns1, nullptr, out_x, nullptr, zero);
  torgb_kernel<<<512, 256, 0, stream>>>(out_x, img, srgb, wrgb, brgb, out_img);
}